// Round 4
// baseline (244.113 us; speedup 1.0000x reference)
//
#include <hip/hip_runtime.h>
#include <hip/hip_bf16.h>

// Single-head causal self-attention, B=4 T=4096 C=1024 H=128, f32 in/out.
// prep_w: W -> Wt bf16 [384][1024] n-major (K|Q|V), Q prescaled by H^-0.5
// proj:   512 blocks x 32 rows; x staged in LDS once, W frags from L2;
//         writes Kb, Qb row-major bf16 and Vt transposed bf16
// attn:   flash causal, QBLK=64 (4 waves x 16 q-rows), kv-split chunk=512,
//         NO K/V LDS staging (direct L2 reads), no inner barriers,
//         XCD-affine block decode (batch pinned to XCD pair)
// combine: merge <=8 kv-split partials per 64-row q-tile
//
// ws map (bytes):
//   Wt    [0,        786432)
//   Qb    [786432,   +4MB)
//   Kb    [+4MB)
//   Vt    [+4MB)                      -> 13369344
//   Opart [13369344, 1152*32KB)       -> 51118080
//   ml    [51118080, +589824)         -> 51707904

typedef unsigned short u16;
typedef __attribute__((ext_vector_type(8))) __bf16 bf16x8;
typedef __attribute__((ext_vector_type(8))) u16 u16x8;
typedef __attribute__((ext_vector_type(4))) u16 u16x4;
typedef __attribute__((ext_vector_type(4))) float f32x4;

#define T_DIM 4096
#define C_DIM 1024
#define H_DIM 128
#define NPB 288  // split entries per batch (chunk = 8 kv-tiles = 512 pos)
#define WS_SPLIT_NEED 51707904ull

static __device__ __forceinline__ f32x4 mfma16x16(u16x8 a, u16x8 b, f32x4 c) {
  return __builtin_amdgcn_mfma_f32_16x16x32_bf16(
      __builtin_bit_cast(bf16x8, a), __builtin_bit_cast(bf16x8, b), c, 0, 0, 0);
}

static __device__ __forceinline__ u16 f2bf(float f) {
  __hip_bfloat16 h = __float2bfloat16(f);
  return __builtin_bit_cast(u16, h);
}

// ---------------------------------------------------------------- prep_w ----
// Wt[n384][k]: n384 = [0,128) K, [128,256) Q (prescaled), [256,384) V.
__global__ __launch_bounds__(256) void prep_w_kernel(
    const float* __restrict__ wk, const float* __restrict__ wq,
    const float* __restrict__ wv, u16* __restrict__ Wt) {
  int idx = blockIdx.x * 256 + threadIdx.x;  // 3*128*1024 exact
  int w = idx >> 17;
  int r = idx & 131071;
  int n = r >> 10;
  int k = r & 1023;
  const float* W = (w == 0) ? wk : (w == 1) ? wq : wv;
  float v = W[k * H_DIM + n];
  if (w == 1) v *= 0.08838834764831845f;  // fold 128^-0.5 into Wq
  Wt[idx] = f2bf(v);
}

// ------------------------------------------------------------------ proj ----
// 512 blocks x 32 rows, 4 waves. x staged in LDS (128 k/iter, bf16); W frags
// direct from L2 (Wt fully L2-resident). Wave w owns cols f*64+w*16+lq,
// f=0,1 -> K; 2,3 -> Q; 4,5 -> V (V transposed via LDS at the end).
__global__ __launch_bounds__(256) void proj_kernel(
    const float* __restrict__ x, const u16* __restrict__ Wt,
    u16* __restrict__ Qb, u16* __restrict__ Kb, u16* __restrict__ Vt) {
  __shared__ __attribute__((aligned(16))) u16 Xl[32 * 136];
  __shared__ __attribute__((aligned(16))) u16 Vs[128 * 40];
  const int m0 = blockIdx.x * 32;
  const int t = threadIdx.x;
  const int wave = t >> 6, lane = t & 63;
  const int g = lane >> 4, lq = lane & 15;

  f32x4 acc[2][6] = {};

  for (int k0 = 0; k0 < C_DIM; k0 += 128) {
    __syncthreads();
#pragma unroll
    for (int p = 0; p < 4; ++p) {  // stage x 32x128 f32 -> bf16
      int idx = p * 256 + t;
      int row = idx >> 5, c4 = (idx & 31) * 4;
      float4 v = *(const float4*)&x[(size_t)(m0 + row) * C_DIM + k0 + c4];
      u16x4 bv;
      bv.x = f2bf(v.x); bv.y = f2bf(v.y); bv.z = f2bf(v.z); bv.w = f2bf(v.w);
      *(u16x4*)&Xl[row * 136 + c4] = bv;
    }
    __syncthreads();
#pragma unroll
    for (int c = 0; c < 4; ++c) {
      u16x8 bfr[6];
#pragma unroll
      for (int f = 0; f < 6; ++f)
        bfr[f] = *(const u16x8*)&Wt[(size_t)(f * 64 + wave * 16 + lq) * C_DIM +
                                    k0 + c * 32 + g * 8];
      u16x8 a[2];
#pragma unroll
      for (int rf = 0; rf < 2; ++rf)
        a[rf] = *(const u16x8*)&Xl[(rf * 16 + lq) * 136 + c * 32 + g * 8];
#pragma unroll
      for (int rf = 0; rf < 2; ++rf)
#pragma unroll
        for (int f = 0; f < 6; ++f)
          acc[rf][f] = mfma16x16(a[rf], bfr[f], acc[rf][f]);
    }
  }

  // K, Q epilogue (row = m0 + rf*16 + g*4 + r, col = f*64 + wave*16 + lq)
#pragma unroll
  for (int f = 0; f < 2; ++f) {
    const int col = f * 64 + wave * 16 + lq;
#pragma unroll
    for (int rf = 0; rf < 2; ++rf)
#pragma unroll
      for (int r = 0; r < 4; ++r) {
        size_t row = (size_t)(m0 + rf * 16 + g * 4 + r);
        Kb[row * H_DIM + col] = f2bf(acc[rf][f][r]);
        Qb[row * H_DIM + col] = f2bf(acc[rf][2 + f][r]);
      }
  }
  // V: transpose via LDS -> Vt[b][h][t]
#pragma unroll
  for (int f = 0; f < 2; ++f)
#pragma unroll
    for (int rf = 0; rf < 2; ++rf)
#pragma unroll
      for (int r = 0; r < 4; ++r)
        Vs[(f * 64 + wave * 16 + lq) * 40 + rf * 16 + g * 4 + r] =
            f2bf(acc[rf][4 + f][r]);
  __syncthreads();
  {
    const int b = m0 >> 12, t0 = m0 & 4095;
#pragma unroll
    for (int p = 0; p < 2; ++p) {
      int idx = p * 256 + t;
      int h = idx >> 2, mc = (idx & 3) * 8;
      *(u16x8*)&Vt[(size_t)b * (H_DIM * T_DIM) + (size_t)h * T_DIM + t0 + mc] =
          *(const u16x8*)&Vs[h * 40 + mc];
    }
  }
}

// ------------------------------------------------------------------ attn ----
// QBLK=64, 4 waves x 16 q-rows. K/V read directly from global (L2-resident;
// XCD-affine decode pins batch to an XCD pair). Only LDS use: per-wave P
// transpose buffer -> no barriers anywhere in the kv loop.
__global__ __launch_bounds__(256) void attn_kernel(
    const u16* __restrict__ Qb, const u16* __restrict__ Kb,
    const u16* __restrict__ Vt, float* __restrict__ out,
    float* __restrict__ Opart, float* __restrict__ ml, int split) {
  __shared__ __attribute__((aligned(16))) u16 Pl[4][16 * 72];
  const int t = threadIdx.x;
  const int wave = t >> 6, lane = t & 63;
  const int g = lane >> 4, lq = lane & 15;

  int b, qt, kvb, kve, pid;
  if (split) {
    int bid = (int)blockIdx.x;   // 1152 linear
    int xcd = bid & 7;
    b = xcd >> 1;                // batch pinned to XCD pair -> K/V L2-local
    int e = (NPB - 1) - ((bid >> 3) * 2 + (bid & 1));  // heavy-first
    int a = 0;
#pragma unroll
    for (int c = 1; c < 8; ++c)
      if (e >= 4 * c * (c + 1)) a = c;
    int off = e - 4 * a * (a + 1);
    int npc = a + 1;
    int d = off / npc;
    qt = 8 * a + d;
    int ch = off - d * npc;
    kvb = ch * 512;
    pid = b * NPB + e;
    int kv_full = qt * 64 + 64;
    kve = (kvb + 512 < kv_full) ? kvb + 512 : kv_full;
  } else {
    b = (int)blockIdx.x & 3;
    qt = 63 - ((int)blockIdx.x >> 2);
    kvb = 0;
    kve = qt * 64 + 64;
    pid = 0;
  }
  const int q0 = qt * 64;
  const int rowq = q0 + wave * 16;  // wave's first q-row

  u16x8 qf[4];  // 16 q-rows x 128, A-frag layout (prescaled)
  {
    const u16* Qp = Qb + (size_t)(b * T_DIM + rowq + lq) * H_DIM;
#pragma unroll
    for (int c = 0; c < 4; ++c) qf[c] = *(const u16x8*)&Qp[c * 32 + g * 8];
  }

  f32x4 ao[8] = {};
  float m_run[4], l_run[4];
#pragma unroll
  for (int r = 0; r < 4; ++r) { m_run[r] = -INFINITY; l_run[r] = 0.f; }

  const u16* Kg0 = Kb + (size_t)b * T_DIM * H_DIM;
  const u16* Vg0 = Vt + (size_t)b * H_DIM * T_DIM;

  for (int kv0 = kvb; kv0 < kve; kv0 += 64) {
    if (kv0 > rowq + 15) break;  // this and all later tiles fully masked

    // S = Q K^T (Q prescaled); K frags straight from L2
    f32x4 s[4];
#pragma unroll
    for (int nf = 0; nf < 4; ++nf) s[nf] = f32x4{0.f, 0.f, 0.f, 0.f};
#pragma unroll
    for (int nf = 0; nf < 4; ++nf) {
      const u16* Kr = Kg0 + (size_t)(kv0 + nf * 16 + lq) * H_DIM;
#pragma unroll
      for (int c = 0; c < 4; ++c) {
        u16x8 kf = *(const u16x8*)&Kr[c * 32 + g * 8];
        s[nf] = mfma16x16(qf[c], kf, s[nf]);
      }
    }

    if (kv0 + 63 > rowq) {  // diagonal overlap: elementwise causal mask
      int row = rowq + g * 4;
#pragma unroll
      for (int nf = 0; nf < 4; ++nf) {
        int col = kv0 + nf * 16 + lq;
#pragma unroll
        for (int r = 0; r < 4; ++r)
          if (col > row + r) s[nf][r] = -INFINITY;
      }
    }

    // online softmax; rows 4g..4g+3 live in 16-lane group g
    float mloc[4];
#pragma unroll
    for (int r = 0; r < 4; ++r)
      mloc[r] = fmaxf(fmaxf(s[0][r], s[1][r]), fmaxf(s[2][r], s[3][r]));
#pragma unroll
    for (int off = 1; off < 16; off <<= 1)
#pragma unroll
      for (int r = 0; r < 4; ++r)
        mloc[r] = fmaxf(mloc[r], __shfl_xor(mloc[r], off));

    float al[4], ps[4];
#pragma unroll
    for (int r = 0; r < 4; ++r) {
      float mn = fmaxf(m_run[r], mloc[r]);
      al[r] = __expf(m_run[r] - mn);
      m_run[r] = mn;
      ps[r] = 0.f;
    }
#pragma unroll
    for (int nf = 0; nf < 4; ++nf)
#pragma unroll
      for (int r = 0; r < 4; ++r) {
        float p = __expf(s[nf][r] - m_run[r]);
        s[nf][r] = p;
        ps[r] += p;
      }
#pragma unroll
    for (int off = 1; off < 16; off <<= 1)
#pragma unroll
      for (int r = 0; r < 4; ++r) ps[r] += __shfl_xor(ps[r], off);
#pragma unroll
    for (int r = 0; r < 4; ++r) l_run[r] = l_run[r] * al[r] + ps[r];
#pragma unroll
    for (int h8 = 0; h8 < 8; ++h8)
#pragma unroll
      for (int r = 0; r < 4; ++r) ao[h8][r] *= al[r];

    // P (D-layout) -> per-wave LDS -> A-layout frags; V straight from L2
#pragma unroll
    for (int nf = 0; nf < 4; ++nf)
#pragma unroll
      for (int r = 0; r < 4; ++r)
        Pl[wave][(g * 4 + r) * 72 + nf * 16 + lq] = f2bf(s[nf][r]);

    u16x8 pf[2];
#pragma unroll
    for (int kk = 0; kk < 2; ++kk)
      pf[kk] = *(const u16x8*)&Pl[wave][lq * 72 + kk * 32 + g * 8];
#pragma unroll
    for (int h8 = 0; h8 < 8; ++h8) {
      const u16* Vr = Vg0 + (size_t)(h8 * 16 + lq) * T_DIM + kv0;
#pragma unroll
      for (int kk = 0; kk < 2; ++kk) {
        u16x8 vf = *(const u16x8*)&Vr[kk * 32 + g * 8];
        ao[h8] = mfma16x16(pf[kk], vf, ao[h8]);
      }
    }
  }

  if (!split) {
    float inv[4];
#pragma unroll
    for (int r = 0; r < 4; ++r) inv[r] = 1.f / l_run[r];
    float* Og = out + (size_t)(b * T_DIM + rowq) * H_DIM;
#pragma unroll
    for (int h8 = 0; h8 < 8; ++h8)
#pragma unroll
      for (int r = 0; r < 4; ++r)
        Og[(size_t)(g * 4 + r) * H_DIM + h8 * 16 + lq] = ao[h8][r] * inv[r];
  } else {
    float* Op = Opart + (size_t)pid * 8192 + (size_t)(wave * 16) * H_DIM;
#pragma unroll
    for (int h8 = 0; h8 < 8; ++h8)
#pragma unroll
      for (int r = 0; r < 4; ++r)
        Op[(size_t)(g * 4 + r) * H_DIM + h8 * 16 + lq] = ao[h8][r];
    if (lq == 0) {
      float* mlp = ml + (size_t)pid * 128;
#pragma unroll
      for (int r = 0; r < 4; ++r) {
        mlp[wave * 16 + g * 4 + r] = m_run[r];
        mlp[64 + wave * 16 + g * 4 + r] = l_run[r];
      }
    }
  }
}

// --------------------------------------------------------------- combine ----
// grid (64, 4): merge the <=8 kv-split partials of one 64-row q-tile.
__global__ __launch_bounds__(256) void combine_kernel(
    const float* __restrict__ Opart, const float* __restrict__ ml,
    float* __restrict__ out) {
  const int qt = blockIdx.x, b = blockIdx.y;
  const int t = threadIdx.x;
  const int row = t >> 2;
  const int colb = (t & 3) * 32;
  const int gg = qt >> 3;
  const int n = gg + 1;
  const int base_e = 4 * gg * (gg + 1) + (qt - 8 * gg) * n;
  const int pid0 = b * NPB + base_e;

  float mv[8];
#pragma unroll
  for (int i = 0; i < 8; ++i)
    mv[i] = (i < n) ? ml[(size_t)(pid0 + i) * 128 + row] : -INFINITY;
  float M = mv[0];
#pragma unroll
  for (int i = 1; i < 8; ++i) M = fmaxf(M, mv[i]);

  float L = 0.f;
  f32x4 o[8] = {};
#pragma unroll
  for (int i = 0; i < 8; ++i)
    if (i < n) {
      float sc = __expf(mv[i] - M);
      L += sc * ml[(size_t)(pid0 + i) * 128 + 64 + row];
      const f32x4* Op = (const f32x4*)(Opart + (size_t)(pid0 + i) * 8192 +
                                       (size_t)row * H_DIM + colb);
#pragma unroll
      for (int p = 0; p < 8; ++p) o[p] += sc * Op[p];
    }
  float inv = 1.f / L;
  f32x4* Og = (f32x4*)(out + ((size_t)b * T_DIM + qt * 64 + row) * H_DIM + colb);
#pragma unroll
  for (int p = 0; p < 8; ++p) Og[p] = o[p] * inv;
}

// ---------------------------------------------------------------- launch ----
extern "C" void kernel_launch(void* const* d_in, const int* in_sizes, int n_in,
                              void* d_out, int out_size, void* d_ws,
                              size_t ws_size, hipStream_t stream) {
  const float* x = (const float*)d_in[0];
  const float* wk = (const float*)d_in[1];
  const float* wq = (const float*)d_in[2];
  const float* wv = (const float*)d_in[3];
  float* out = (float*)d_out;
  char* ws = (char*)d_ws;

  u16* Wt = (u16*)ws;
  u16* Qb = (u16*)(ws + 786432);
  u16* Kb = (u16*)(ws + 786432 + 4194304);
  u16* Vt = (u16*)(ws + 786432 + 8388608);
  float* Opart = (float*)(ws + 13369344);
  float* ml = (float*)(ws + 51118080);

  const int split = (ws_size >= WS_SPLIT_NEED) ? 1 : 0;

  prep_w_kernel<<<1536, 256, 0, stream>>>(wk, wq, wv, Wt);
  proj_kernel<<<512, 256, 0, stream>>>(x, Wt, Qb, Kb, Vt);
  if (split) {
    attn_kernel<<<4 * NPB, 256, 0, stream>>>(Qb, Kb, Vt, out, Opart, ml, 1);
    combine_kernel<<<dim3(64, 4), 256, 0, stream>>>(Opart, ml, out);
  } else {
    attn_kernel<<<256, 256, 0, stream>>>(Qb, Kb, Vt, out, Opart, ml, 0);
  }
}

// Round 5
// 155.082 us; speedup vs baseline: 1.5741x; 1.5741x over previous
//
#include <hip/hip_runtime.h>
#include <hip/hip_bf16.h>

// Single-head causal self-attention, B=4 T=4096 C=1024 H=128, f32 in/out.
// prep_w: W -> Wt bf16 [384][1024] n-major (K|Q|V)
// proj:   fused x@{Wk,Wq,Wv}, one x pass (R2 structure), Q prescaled,
//         V written transposed (Vt[b][h][t])
// attn:   flash causal, QBLK=64 (4 waves x 16 q-rows), kv-split chunk=512.
//         K staged in LDS (shared 4 waves); V read DIRECT from L2 (Vt is
//         2MB/batch, XCD-pinned); P via per-wave LDS transpose buffer.
//         LDS 26.6KB -> ~6 blocks/CU resident.
// combine: merge <=8 kv-split partials per 64-row q-tile
//
// ws map (bytes):
//   Wt    [0,        786432)
//   Qb    [786432,   +4MB)
//   Kb    [+4MB)
//   Vt    [+4MB)                      -> 13369344
//   Opart [13369344, 1152*32KB)       -> 51118080
//   ml    [51118080, +589824)         -> 51707904

typedef unsigned short u16;
typedef __attribute__((ext_vector_type(8))) __bf16 bf16x8;
typedef __attribute__((ext_vector_type(8))) u16 u16x8;
typedef __attribute__((ext_vector_type(4))) u16 u16x4;
typedef __attribute__((ext_vector_type(4))) float f32x4;

#define T_DIM 4096
#define C_DIM 1024
#define H_DIM 128
#define NPB 288  // split entries per batch (chunk = 8 kv-tiles = 512 pos)
#define WS_SPLIT_NEED 51707904ull

static __device__ __forceinline__ f32x4 mfma16x16(u16x8 a, u16x8 b, f32x4 c) {
  return __builtin_amdgcn_mfma_f32_16x16x32_bf16(
      __builtin_bit_cast(bf16x8, a), __builtin_bit_cast(bf16x8, b), c, 0, 0, 0);
}

static __device__ __forceinline__ u16 f2bf(float f) {
  __hip_bfloat16 h = __float2bfloat16(f);
  return __builtin_bit_cast(u16, h);
}

// ---------------------------------------------------------------- prep_w ----
// Wt[n384][k]: n384 = [0,128) K, [128,256) Q, [256,384) V.
__global__ __launch_bounds__(256) void prep_w_kernel(
    const float* __restrict__ wk, const float* __restrict__ wq,
    const float* __restrict__ wv, u16* __restrict__ Wt) {
  int idx = blockIdx.x * 256 + threadIdx.x;  // 3*128*1024 exact
  int w = idx >> 17;
  int r = idx & 131071;
  int n = r >> 10;
  int k = r & 1023;
  const float* W = (w == 0) ? wk : (w == 1) ? wq : wv;
  Wt[idx] = f2bf(W[k * H_DIM + n]);
}

// ------------------------------------------------------------------ proj ----
// R2 structure: 256 blocks x 64 rows. One x-tile staging feeds all three Ws.
// wave0 -> Kb, wave1 -> Qb (prescaled by H^-0.5), wave2 -> Vt, wave3 stages.
__global__ __launch_bounds__(256, 1) void proj_kernel(
    const float* __restrict__ x, const u16* __restrict__ Wt,
    u16* __restrict__ Qb, u16* __restrict__ Kb, u16* __restrict__ Vt) {
  __shared__ __attribute__((aligned(16))) u16 smem[64 * 72 + 384 * 72];
  u16* Xl = smem;            // [64][64] pad 72
  u16* Wl = smem + 64 * 72;  // [3*128][64] pad 72
  const int m0 = blockIdx.x * 64;
  const int t = threadIdx.x;
  const int wave = t >> 6, lane = t & 63;
  const int g = lane >> 4, lq = lane & 15;

  f32x4 acc[4][8] = {};

  for (int k0 = 0; k0 < C_DIM; k0 += 64) {
    __syncthreads();
#pragma unroll
    for (int p = 0; p < 4; ++p) {  // stage x: 64x64 f32 -> bf16
      int idx = p * 256 + t;
      int row = idx >> 4, c4 = (idx & 15) * 4;
      float4 v = *(const float4*)&x[(size_t)(m0 + row) * C_DIM + k0 + c4];
      u16x4 bv;
      bv.x = f2bf(v.x); bv.y = f2bf(v.y); bv.z = f2bf(v.z); bv.w = f2bf(v.w);
      *(u16x4*)&Xl[row * 72 + c4] = bv;
    }
#pragma unroll
    for (int p = 0; p < 12; ++p) {  // stage Wt: 384 rows x 64 k
      int idx = p * 256 + t;
      int wrow = idx >> 3, col = (idx & 7) * 8;
      *(u16x8*)&Wl[wrow * 72 + col] =
          *(const u16x8*)&Wt[(size_t)(wrow >> 7) * 131072 +
                             (size_t)(wrow & 127) * 1024 + k0 + col];
    }
    __syncthreads();
    if (wave < 3) {
#pragma unroll
      for (int kk = 0; kk < 2; ++kk) {
        u16x8 af[4], bfr[8];
#pragma unroll
        for (int i = 0; i < 4; ++i)
          af[i] = *(const u16x8*)&Xl[(i * 16 + lq) * 72 + kk * 32 + g * 8];
#pragma unroll
        for (int j = 0; j < 8; ++j)
          bfr[j] = *(const u16x8*)&Wl[(wave * 128 + j * 16 + lq) * 72 +
                                      kk * 32 + g * 8];
#pragma unroll
        for (int i = 0; i < 4; ++i)
#pragma unroll
          for (int j = 0; j < 8; ++j)
            acc[i][j] = mfma16x16(af[i], bfr[j], acc[i][j]);
      }
    }
  }

  const float qscale = 0.08838834764831845f;  // 128^-0.5
  if (wave == 0) {
#pragma unroll
    for (int i = 0; i < 4; ++i)
#pragma unroll
      for (int j = 0; j < 8; ++j)
#pragma unroll
        for (int r = 0; r < 4; ++r)
          Kb[(size_t)(m0 + i * 16 + g * 4 + r) * H_DIM + j * 16 + lq] =
              f2bf(acc[i][j][r]);
  }
  if (wave == 1) {
#pragma unroll
    for (int i = 0; i < 4; ++i)
#pragma unroll
      for (int j = 0; j < 8; ++j)
#pragma unroll
        for (int r = 0; r < 4; ++r)
          Qb[(size_t)(m0 + i * 16 + g * 4 + r) * H_DIM + j * 16 + lq] =
              f2bf(acc[i][j][r] * qscale);
  }
  __syncthreads();
  if (wave == 2) {  // V -> LDS transposed [128 h][64 m] stride 72
#pragma unroll
    for (int i = 0; i < 4; ++i)
#pragma unroll
      for (int j = 0; j < 8; ++j)
#pragma unroll
        for (int r = 0; r < 4; ++r)
          smem[(j * 16 + lq) * 72 + i * 16 + g * 4 + r] = f2bf(acc[i][j][r]);
  }
  __syncthreads();
  {
    const int b = m0 >> 12;
    const int t0 = m0 & 4095;
#pragma unroll
    for (int p = 0; p < 4; ++p) {
      int idx = p * 256 + t;
      int h = idx >> 3, mc = (idx & 7) * 8;
      *(u16x8*)&Vt[(size_t)b * (H_DIM * T_DIM) + (size_t)h * T_DIM + t0 + mc] =
          *(const u16x8*)&smem[h * 72 + mc];
    }
  }
}

// ------------------------------------------------------------------ attn ----
// QBLK=64, 4 waves x 16 q-rows. K staged in LDS; V direct from L2 (Vt).
// split: 1152 linear blocks, XCD-pinned batch (bid&7 -> XCD pair), heavy
// chunks first within each XCD. LDS 26.6KB -> ~6 blocks/CU.
__global__ __launch_bounds__(256, 4) void attn_kernel(
    const u16* __restrict__ Qb, const u16* __restrict__ Kb,
    const u16* __restrict__ Vt, float* __restrict__ out,
    float* __restrict__ Opart, float* __restrict__ ml, int split) {
  __shared__ __attribute__((aligned(16))) u16 Kl[64 * 136];
  __shared__ __attribute__((aligned(16))) u16 Pl[4][16 * 72];
  const int t = threadIdx.x;
  const int wave = t >> 6, lane = t & 63;
  const int g = lane >> 4, lq = lane & 15;

  int b, qt, kvb, kve, pid;
  if (split) {
    int bid = (int)blockIdx.x;  // 1152 linear
    int xcd = bid & 7;
    b = xcd >> 1;  // batch pinned to an XCD pair -> K/V L2-local
    int e = (NPB - 1) - ((bid >> 3) * 2 + (bid & 1));  // heavy-first
    int a = 0;
#pragma unroll
    for (int c = 1; c < 8; ++c)
      if (e >= 4 * c * (c + 1)) a = c;
    int off = e - 4 * a * (a + 1);
    int npc = a + 1;
    int d = off / npc;
    qt = 8 * a + d;
    int ch = off - d * npc;
    kvb = ch * 512;
    pid = b * NPB + e;
    int kv_full = qt * 64 + 64;
    kve = (kvb + 512 < kv_full) ? kvb + 512 : kv_full;
  } else {
    b = (int)blockIdx.x & 3;
    qt = 63 - ((int)blockIdx.x >> 2);
    kvb = 0;
    kve = qt * 64 + 64;
    pid = 0;
  }
  const int q0 = qt * 64;
  const int rowq = q0 + wave * 16;  // wave's first q-row

  u16x8 qf[4];  // 16 q-rows x 128, A-frag layout (prescaled)
  {
    const u16* Qp = Qb + (size_t)(b * T_DIM + rowq + lq) * H_DIM;
#pragma unroll
    for (int c = 0; c < 4; ++c) qf[c] = *(const u16x8*)&Qp[c * 32 + g * 8];
  }

  f32x4 ao[8] = {};
  float m_run[4], l_run[4];
#pragma unroll
  for (int r = 0; r < 4; ++r) { m_run[r] = -INFINITY; l_run[r] = 0.f; }

  const int krow = t >> 4, kcol = (t & 15) * 8;
  const u16* Kg0 = Kb + (size_t)b * T_DIM * H_DIM;
  const u16* Vg0 = Vt + (size_t)b * H_DIM * T_DIM;

  for (int kv0 = kvb; kv0 < kve; kv0 += 64) {
    __syncthreads();
#pragma unroll
    for (int p = 0; p < 4; ++p) {  // K tile [64][128] -> [64][136]
      int r = p * 16 + krow;
      *(u16x8*)&Kl[r * 136 + kcol] =
          *(const u16x8*)&Kg0[(size_t)(kv0 + r) * H_DIM + kcol];
    }
    __syncthreads();

    // S = Q K^T (Q prescaled): 4 col-frags x 4 k-chunks from LDS
    f32x4 s[4];
#pragma unroll
    for (int nf = 0; nf < 4; ++nf) s[nf] = f32x4{0.f, 0.f, 0.f, 0.f};
#pragma unroll
    for (int nf = 0; nf < 4; ++nf)
#pragma unroll
      for (int c = 0; c < 4; ++c) {
        u16x8 kf = *(const u16x8*)&Kl[(nf * 16 + lq) * 136 + c * 32 + g * 8];
        s[nf] = mfma16x16(qf[c], kf, s[nf]);
      }

    if (kv0 + 63 > rowq) {  // diagonal overlap: elementwise causal mask
      int row = rowq + g * 4;
#pragma unroll
      for (int nf = 0; nf < 4; ++nf) {
        int col = kv0 + nf * 16 + lq;
#pragma unroll
        for (int r = 0; r < 4; ++r)
          if (col > row + r) s[nf][r] = -INFINITY;
      }
    }

    // online softmax; rows 4g..4g+3 live in 16-lane group g
    float mloc[4];
#pragma unroll
    for (int r = 0; r < 4; ++r)
      mloc[r] = fmaxf(fmaxf(s[0][r], s[1][r]), fmaxf(s[2][r], s[3][r]));
#pragma unroll
    for (int off = 1; off < 16; off <<= 1)
#pragma unroll
      for (int r = 0; r < 4; ++r)
        mloc[r] = fmaxf(mloc[r], __shfl_xor(mloc[r], off));

    float al[4], ps[4];
#pragma unroll
    for (int r = 0; r < 4; ++r) {
      float mn = fmaxf(m_run[r], mloc[r]);
      al[r] = __expf(m_run[r] - mn);
      m_run[r] = mn;
      ps[r] = 0.f;
    }
#pragma unroll
    for (int nf = 0; nf < 4; ++nf)
#pragma unroll
      for (int r = 0; r < 4; ++r) {
        float p = __expf(s[nf][r] - m_run[r]);
        s[nf][r] = p;
        ps[r] += p;
      }
#pragma unroll
    for (int off = 1; off < 16; off <<= 1)
#pragma unroll
      for (int r = 0; r < 4; ++r) ps[r] += __shfl_xor(ps[r], off);
#pragma unroll
    for (int r = 0; r < 4; ++r) l_run[r] = l_run[r] * al[r] + ps[r];

    // T13 defer-rescale: skip the O-wide pass when max unchanged (wave-uniform)
    bool nochg = (al[0] == 1.f) && (al[1] == 1.f) && (al[2] == 1.f) &&
                 (al[3] == 1.f);
    if (!__all(nochg)) {
#pragma unroll
      for (int h8 = 0; h8 < 8; ++h8)
#pragma unroll
        for (int r = 0; r < 4; ++r) ao[h8][r] *= al[r];
    }

    // P (D-layout) -> per-wave LDS -> A-layout frags; V direct from L2
#pragma unroll
    for (int nf = 0; nf < 4; ++nf)
#pragma unroll
      for (int r = 0; r < 4; ++r)
        Pl[wave][(g * 4 + r) * 72 + nf * 16 + lq] = f2bf(s[nf][r]);

    u16x8 pf[2];
#pragma unroll
    for (int kk = 0; kk < 2; ++kk)
      pf[kk] = *(const u16x8*)&Pl[wave][lq * 72 + kk * 32 + g * 8];
#pragma unroll
    for (int h8 = 0; h8 < 8; ++h8) {
      const u16* Vr = Vg0 + (size_t)(h8 * 16 + lq) * T_DIM + kv0;
#pragma unroll
      for (int kk = 0; kk < 2; ++kk) {
        u16x8 vf = *(const u16x8*)&Vr[kk * 32 + g * 8];
        ao[h8] = mfma16x16(pf[kk], vf, ao[h8]);
      }
    }
  }

  if (!split) {
    float inv[4];
#pragma unroll
    for (int r = 0; r < 4; ++r) inv[r] = 1.f / l_run[r];
    float* Og = out + (size_t)(b * T_DIM + rowq) * H_DIM;
#pragma unroll
    for (int h8 = 0; h8 < 8; ++h8)
#pragma unroll
      for (int r = 0; r < 4; ++r)
        Og[(size_t)(g * 4 + r) * H_DIM + h8 * 16 + lq] = ao[h8][r] * inv[r];
  } else {
    float* Op = Opart + (size_t)pid * 8192 + (size_t)(wave * 16) * H_DIM;
#pragma unroll
    for (int h8 = 0; h8 < 8; ++h8)
#pragma unroll
      for (int r = 0; r < 4; ++r)
        Op[(size_t)(g * 4 + r) * H_DIM + h8 * 16 + lq] = ao[h8][r];
    if (lq == 0) {
      float* mlp = ml + (size_t)pid * 128;
#pragma unroll
      for (int r = 0; r < 4; ++r) {
        mlp[wave * 16 + g * 4 + r] = m_run[r];
        mlp[64 + wave * 16 + g * 4 + r] = l_run[r];
      }
    }
  }
}

// --------------------------------------------------------------- combine ----
// grid (64, 4): merge the <=8 kv-split partials of one 64-row q-tile.
__global__ __launch_bounds__(256) void combine_kernel(
    const float* __restrict__ Opart, const float* __restrict__ ml,
    float* __restrict__ out) {
  const int qt = blockIdx.x, b = blockIdx.y;
  const int t = threadIdx.x;
  const int row = t >> 2;
  const int colb = (t & 3) * 32;
  const int gg = qt >> 3;
  const int n = gg + 1;
  const int base_e = 4 * gg * (gg + 1) + (qt - 8 * gg) * n;
  const int pid0 = b * NPB + base_e;

  float mv[8];
#pragma unroll
  for (int i = 0; i < 8; ++i)
    mv[i] = (i < n) ? ml[(size_t)(pid0 + i) * 128 + row] : -INFINITY;
  float M = mv[0];
#pragma unroll
  for (int i = 1; i < 8; ++i) M = fmaxf(M, mv[i]);

  float L = 0.f;
  f32x4 o[8] = {};
#pragma unroll
  for (int i = 0; i < 8; ++i)
    if (i < n) {
      float sc = __expf(mv[i] - M);
      L += sc * ml[(size_t)(pid0 + i) * 128 + 64 + row];
      const f32x4* Op = (const f32x4*)(Opart + (size_t)(pid0 + i) * 8192 +
                                       (size_t)row * H_DIM + colb);
#pragma unroll
      for (int p = 0; p < 8; ++p) o[p] += sc * Op[p];
    }
  float inv = 1.f / L;
  f32x4* Og = (f32x4*)(out + ((size_t)b * T_DIM + qt * 64 + row) * H_DIM + colb);
#pragma unroll
  for (int p = 0; p < 8; ++p) Og[p] = o[p] * inv;
}

// ---------------------------------------------------------------- launch ----
extern "C" void kernel_launch(void* const* d_in, const int* in_sizes, int n_in,
                              void* d_out, int out_size, void* d_ws,
                              size_t ws_size, hipStream_t stream) {
  const float* x = (const float*)d_in[0];
  const float* wk = (const float*)d_in[1];
  const float* wq = (const float*)d_in[2];
  const float* wv = (const float*)d_in[3];
  float* out = (float*)d_out;
  char* ws = (char*)d_ws;

  u16* Wt = (u16*)ws;
  u16* Qb = (u16*)(ws + 786432);
  u16* Kb = (u16*)(ws + 786432 + 4194304);
  u16* Vt = (u16*)(ws + 786432 + 8388608);
  float* Opart = (float*)(ws + 13369344);
  float* ml = (float*)(ws + 51118080);

  const int split = (ws_size >= WS_SPLIT_NEED) ? 1 : 0;

  prep_w_kernel<<<1536, 256, 0, stream>>>(wk, wq, wv, Wt);
  proj_kernel<<<256, 256, 0, stream>>>(x, Wt, Qb, Kb, Vt);
  if (split) {
    attn_kernel<<<4 * NPB, 256, 0, stream>>>(Qb, Kb, Vt, out, Opart, ml, 1);
    combine_kernel<<<dim3(64, 4), 256, 0, stream>>>(Opart, ml, out);
  } else {
    attn_kernel<<<256, 256, 0, stream>>>(Qb, Kb, Vt, out, Opart, ml, 0);
  }
}

// Round 6
// 118.248 us; speedup vs baseline: 2.0644x; 1.3115x over previous
//
#include <hip/hip_runtime.h>
#include <hip/hip_bf16.h>

// Single-head causal self-attention, B=4 T=4096 C=1024 H=128, f32 in/out.
// prep_w: W -> Wt bf16 [3][128][1024] n-major, via LDS transpose (coalesced)
// proj:   fused x@{Wk,Wq,Wv}, one x pass, ALL 4 waves compute (96 cols each);
//         Q prescaled; V written transposed (Vt[b][h][t])
// attn:   flash causal, QBLK=64 (4 waves x 16 q-rows), kv-split chunk=512.
//         K+V staged in LDS with T14 async split: next tile's global loads
//         issued BEFORE compute, ds_write AFTER the post-compute barrier.
//         Partials written as bf16.
// combine: merge <=8 kv-split partials per 64-row q-tile (bf16 partials).
//
// ws map (bytes):
//   Wt    [0,        786432)
//   Qb    [786432,   +4MB)
//   Kb    [+4MB)
//   Vt    [+4MB)                      -> 13369344
//   Opart [13369344, +1152*16KB)      -> 32243712   (bf16)
//   ml    [32243712, +589824)         -> 32833536

typedef unsigned short u16;
typedef __attribute__((ext_vector_type(8))) __bf16 bf16x8;
typedef __attribute__((ext_vector_type(8))) u16 u16x8;
typedef __attribute__((ext_vector_type(4))) u16 u16x4;
typedef __attribute__((ext_vector_type(4))) float f32x4;

#define T_DIM 4096
#define C_DIM 1024
#define H_DIM 128
#define NPB 288  // split entries per batch (chunk = 8 kv-tiles = 512 pos)
#define WS_SPLIT_NEED 32833536ull

static __device__ __forceinline__ f32x4 mfma16x16(u16x8 a, u16x8 b, f32x4 c) {
  return __builtin_amdgcn_mfma_f32_16x16x32_bf16(
      __builtin_bit_cast(bf16x8, a), __builtin_bit_cast(bf16x8, b), c, 0, 0, 0);
}

static __device__ __forceinline__ u16 f2bf(float f) {
  __hip_bfloat16 h = __float2bfloat16(f);
  return __builtin_bit_cast(u16, h);
}

static __device__ __forceinline__ float bf2f(u16 u) {
  unsigned x = (unsigned)u << 16;
  return __builtin_bit_cast(float, x);
}

// ---------------------------------------------------------------- prep_w ----
// grid (16, 3): transpose one 64k x 128n slab of W_w via LDS. Coalesced reads
// AND writes (old version did 512B-strided f32 reads -> ~25MB overfetch).
__global__ __launch_bounds__(256) void prep_w_kernel(
    const float* __restrict__ wk, const float* __restrict__ wq,
    const float* __restrict__ wv, u16* __restrict__ Wt) {
  __shared__ u16 L[64 * 136];
  const int w = blockIdx.y;
  const int k0 = blockIdx.x * 64;
  const float* W = (w == 0) ? wk : (w == 1) ? wq : wv;
  const int t = threadIdx.x;
#pragma unroll
  for (int p = 0; p < 8; ++p) {  // 64 k-rows x 128 n f32, coalesced
    int idx = p * 256 + t;
    int k = idx >> 5, c4 = (idx & 31) * 4;
    float4 v = *(const float4*)&W[(size_t)(k0 + k) * H_DIM + c4];
    u16x4 bv;
    bv.x = f2bf(v.x); bv.y = f2bf(v.y); bv.z = f2bf(v.z); bv.w = f2bf(v.w);
    *(u16x4*)&L[k * 136 + c4] = bv;
  }
  __syncthreads();
#pragma unroll
  for (int p = 0; p < 4; ++p) {  // write Wt[w][n][k0+..] in 16B chunks
    int cid = p * 256 + t;
    int n = cid >> 3, kc = (cid & 7) * 8;
    u16x8 o;
#pragma unroll
    for (int j = 0; j < 8; ++j) o[j] = L[(kc + j) * 136 + n];
    *(u16x8*)&Wt[(size_t)w * 131072 + (size_t)n * 1024 + k0 + kc] = o;
  }
}

// ------------------------------------------------------------------ proj ----
// 256 blocks x 64 rows. One x-tile staging feeds all three Ws; all 4 waves
// compute: wave owns output cols384 wave*96 + j*16 + lq, j=0..5
// (cols384: [0,128)=K, [128,256)=Q prescaled, [256,384)=V transposed).
__global__ __launch_bounds__(256, 1) void proj_kernel(
    const float* __restrict__ x, const u16* __restrict__ Wt,
    u16* __restrict__ Qb, u16* __restrict__ Kb, u16* __restrict__ Vt) {
  __shared__ __attribute__((aligned(16))) u16 smem[64 * 72 + 384 * 72];
  u16* Xl = smem;            // [64][64] pad 72
  u16* Wl = smem + 64 * 72;  // [384][64] pad 72
  const int m0 = blockIdx.x * 64;
  const int t = threadIdx.x;
  const int wave = t >> 6, lane = t & 63;
  const int g = lane >> 4, lq = lane & 15;

  f32x4 acc[4][6] = {};

  for (int k0 = 0; k0 < C_DIM; k0 += 64) {
    __syncthreads();
#pragma unroll
    for (int p = 0; p < 4; ++p) {  // stage x: 64x64 f32 -> bf16
      int idx = p * 256 + t;
      int row = idx >> 4, c4 = (idx & 15) * 4;
      float4 v = *(const float4*)&x[(size_t)(m0 + row) * C_DIM + k0 + c4];
      u16x4 bv;
      bv.x = f2bf(v.x); bv.y = f2bf(v.y); bv.z = f2bf(v.z); bv.w = f2bf(v.w);
      *(u16x4*)&Xl[row * 72 + c4] = bv;
    }
#pragma unroll
    for (int p = 0; p < 12; ++p) {  // stage Wt: 384 rows x 64 k
      int idx = p * 256 + t;
      int wrow = idx >> 3, col = (idx & 7) * 8;
      *(u16x8*)&Wl[wrow * 72 + col] =
          *(const u16x8*)&Wt[(size_t)(wrow >> 7) * 131072 +
                             (size_t)(wrow & 127) * 1024 + k0 + col];
    }
    __syncthreads();
#pragma unroll
    for (int kk = 0; kk < 2; ++kk) {
      u16x8 af[4], bfr[6];
#pragma unroll
      for (int i = 0; i < 4; ++i)
        af[i] = *(const u16x8*)&Xl[(i * 16 + lq) * 72 + kk * 32 + g * 8];
#pragma unroll
      for (int j = 0; j < 6; ++j)
        bfr[j] = *(const u16x8*)&Wl[(wave * 96 + j * 16 + lq) * 72 + kk * 32 +
                                    g * 8];
#pragma unroll
      for (int i = 0; i < 4; ++i)
#pragma unroll
        for (int j = 0; j < 6; ++j)
          acc[i][j] = mfma16x16(af[i], bfr[j], acc[i][j]);
    }
  }

  const float qscale = 0.08838834764831845f;  // 128^-0.5
#pragma unroll
  for (int j = 0; j < 6; ++j) {  // K and Q direct writes
    const int c384 = wave * 96 + j * 16;  // wave-uniform
    const int which = c384 >> 7;
    const int col = (c384 & 127) + lq;
    if (which == 0) {
#pragma unroll
      for (int i = 0; i < 4; ++i)
#pragma unroll
        for (int r = 0; r < 4; ++r)
          Kb[(size_t)(m0 + i * 16 + g * 4 + r) * H_DIM + col] =
              f2bf(acc[i][j][r]);
    } else if (which == 1) {
#pragma unroll
      for (int i = 0; i < 4; ++i)
#pragma unroll
        for (int r = 0; r < 4; ++r)
          Qb[(size_t)(m0 + i * 16 + g * 4 + r) * H_DIM + col] =
              f2bf(acc[i][j][r] * qscale);
    }
  }
  __syncthreads();
#pragma unroll
  for (int j = 0; j < 6; ++j) {  // V -> LDS transposed [128 h][64 m] pad 72
    const int c384 = wave * 96 + j * 16;
    if ((c384 >> 7) == 2) {
      const int v = (c384 & 127) + lq;
#pragma unroll
      for (int i = 0; i < 4; ++i)
#pragma unroll
        for (int r = 0; r < 4; ++r)
          smem[v * 72 + i * 16 + g * 4 + r] = f2bf(acc[i][j][r]);
    }
  }
  __syncthreads();
  {
    const int b = m0 >> 12;
    const int t0 = m0 & 4095;
#pragma unroll
    for (int p = 0; p < 4; ++p) {
      int idx = p * 256 + t;
      int h = idx >> 3, mc = (idx & 7) * 8;
      *(u16x8*)&Vt[(size_t)b * (H_DIM * T_DIM) + (size_t)h * T_DIM + t0 + mc] =
          *(const u16x8*)&smem[h * 72 + mc];
    }
  }
}

// ------------------------------------------------------------------ attn ----
// QBLK=64, 4 waves x 16 q-rows, K+V LDS-staged with T14 async split:
// issue next-tile global loads before compute, ds_write after barrier.
// split: 1152 linear blocks, XCD-pinned batch, heavy chunks first.
__global__ __launch_bounds__(256, 4) void attn_kernel(
    const u16* __restrict__ Qb, const u16* __restrict__ Kb,
    const u16* __restrict__ Vt, float* __restrict__ out,
    u16* __restrict__ Opart, float* __restrict__ ml, int split) {
  __shared__ __attribute__((aligned(16))) u16 Kl[64 * 136];
  __shared__ __attribute__((aligned(16))) u16 Vl[128 * 72];
  __shared__ __attribute__((aligned(16))) u16 Pl[4][16 * 72];
  const int t = threadIdx.x;
  const int wave = t >> 6, lane = t & 63;
  const int g = lane >> 4, lq = lane & 15;

  int b, qt, kvb, kve, pid;
  if (split) {
    int bid = (int)blockIdx.x;  // 1152 linear
    int xcd = bid & 7;
    b = xcd >> 1;  // batch pinned to an XCD pair -> K/V L2-local
    int e = (NPB - 1) - ((bid >> 3) * 2 + (bid & 1));  // heavy-first
    int a = 0;
#pragma unroll
    for (int c = 1; c < 8; ++c)
      if (e >= 4 * c * (c + 1)) a = c;
    int off = e - 4 * a * (a + 1);
    int npc = a + 1;
    int d = off / npc;
    qt = 8 * a + d;
    int ch = off - d * npc;
    kvb = ch * 512;
    pid = b * NPB + e;
    int kv_full = qt * 64 + 64;
    kve = (kvb + 512 < kv_full) ? kvb + 512 : kv_full;
  } else {
    b = (int)blockIdx.x & 3;
    qt = 63 - ((int)blockIdx.x >> 2);
    kvb = 0;
    kve = qt * 64 + 64;
    pid = 0;
  }
  const int q0 = qt * 64;
  const int rowq = q0 + wave * 16;  // wave's first q-row

  u16x8 qf[4];  // 16 q-rows x 128, A-frag layout (prescaled)
  {
    const u16* Qp = Qb + (size_t)(b * T_DIM + rowq + lq) * H_DIM;
#pragma unroll
    for (int c = 0; c < 4; ++c) qf[c] = *(const u16x8*)&Qp[c * 32 + g * 8];
  }

  f32x4 ao[8] = {};
  float m_run[4], l_run[4];
#pragma unroll
  for (int r = 0; r < 4; ++r) { m_run[r] = -INFINITY; l_run[r] = 0.f; }

  const int krow = t >> 4, kcol = (t & 15) * 8;
  const int vrow = t >> 3, vcol = (t & 7) * 8;
  const u16* Kg0 = Kb + (size_t)b * T_DIM * H_DIM;
  const u16* Vg0 = Vt + (size_t)b * H_DIM * T_DIM;

  u16x8 kreg[4], vreg[4];
  // prologue: stage first tile
#pragma unroll
  for (int p = 0; p < 4; ++p)
    kreg[p] = *(const u16x8*)&Kg0[(size_t)(kvb + p * 16 + krow) * H_DIM + kcol];
#pragma unroll
  for (int p = 0; p < 4; ++p)
    vreg[p] = *(const u16x8*)&Vg0[(size_t)(p * 32 + vrow) * T_DIM + kvb + vcol];
#pragma unroll
  for (int p = 0; p < 4; ++p)
    *(u16x8*)&Kl[(p * 16 + krow) * 136 + kcol] = kreg[p];
#pragma unroll
  for (int p = 0; p < 4; ++p)
    *(u16x8*)&Vl[(p * 32 + vrow) * 72 + vcol] = vreg[p];
  __syncthreads();

  for (int kv0 = kvb; kv0 < kve; kv0 += 64) {
    const bool nxt = (kv0 + 64) < kve;  // block-uniform
    if (nxt) {  // T14: issue next tile's loads BEFORE compute
      const int kn = kv0 + 64;
#pragma unroll
      for (int p = 0; p < 4; ++p)
        kreg[p] =
            *(const u16x8*)&Kg0[(size_t)(kn + p * 16 + krow) * H_DIM + kcol];
#pragma unroll
      for (int p = 0; p < 4; ++p)
        vreg[p] =
            *(const u16x8*)&Vg0[(size_t)(p * 32 + vrow) * T_DIM + kn + vcol];
    }

    // S = Q K^T (Q prescaled): 4 col-frags x 4 k-chunks from LDS
    f32x4 s[4];
#pragma unroll
    for (int nf = 0; nf < 4; ++nf) s[nf] = f32x4{0.f, 0.f, 0.f, 0.f};
#pragma unroll
    for (int nf = 0; nf < 4; ++nf)
#pragma unroll
      for (int c = 0; c < 4; ++c) {
        u16x8 kf = *(const u16x8*)&Kl[(nf * 16 + lq) * 136 + c * 32 + g * 8];
        s[nf] = mfma16x16(qf[c], kf, s[nf]);
      }

    if (kv0 + 63 > rowq) {  // diagonal overlap: elementwise causal mask
      int row = rowq + g * 4;
#pragma unroll
      for (int nf = 0; nf < 4; ++nf) {
        int col = kv0 + nf * 16 + lq;
#pragma unroll
        for (int r = 0; r < 4; ++r)
          if (col > row + r) s[nf][r] = -INFINITY;
      }
    }

    // online softmax; rows 4g..4g+3 live in 16-lane group g
    float mloc[4];
#pragma unroll
    for (int r = 0; r < 4; ++r)
      mloc[r] = fmaxf(fmaxf(s[0][r], s[1][r]), fmaxf(s[2][r], s[3][r]));
#pragma unroll
    for (int off = 1; off < 16; off <<= 1)
#pragma unroll
      for (int r = 0; r < 4; ++r)
        mloc[r] = fmaxf(mloc[r], __shfl_xor(mloc[r], off));

    float al[4], ps[4];
#pragma unroll
    for (int r = 0; r < 4; ++r) {
      float mn = fmaxf(m_run[r], mloc[r]);
      al[r] = __expf(m_run[r] - mn);
      m_run[r] = mn;
      ps[r] = 0.f;
    }
#pragma unroll
    for (int nf = 0; nf < 4; ++nf)
#pragma unroll
      for (int r = 0; r < 4; ++r) {
        float p = __expf(s[nf][r] - m_run[r]);
        s[nf][r] = p;
        ps[r] += p;
      }
#pragma unroll
    for (int off = 1; off < 16; off <<= 1)
#pragma unroll
      for (int r = 0; r < 4; ++r) ps[r] += __shfl_xor(ps[r], off);
#pragma unroll
    for (int r = 0; r < 4; ++r) l_run[r] = l_run[r] * al[r] + ps[r];

    // T13 defer-rescale: skip O-wide pass when max unchanged (wave-uniform)
    bool nochg = (al[0] == 1.f) && (al[1] == 1.f) && (al[2] == 1.f) &&
                 (al[3] == 1.f);
    if (!__all(nochg)) {
#pragma unroll
      for (int h8 = 0; h8 < 8; ++h8)
#pragma unroll
        for (int r = 0; r < 4; ++r) ao[h8][r] *= al[r];
    }

    // P (D-layout) -> per-wave LDS -> A-layout frags
#pragma unroll
    for (int nf = 0; nf < 4; ++nf)
#pragma unroll
      for (int r = 0; r < 4; ++r)
        Pl[wave][(g * 4 + r) * 72 + nf * 16 + lq] = f2bf(s[nf][r]);

    u16x8 pf[2];
#pragma unroll
    for (int kk = 0; kk < 2; ++kk)
      pf[kk] = *(const u16x8*)&Pl[wave][lq * 72 + kk * 32 + g * 8];
#pragma unroll
    for (int h8 = 0; h8 < 8; ++h8)
#pragma unroll
      for (int kk = 0; kk < 2; ++kk) {
        u16x8 vf = *(const u16x8*)&Vl[(h8 * 16 + lq) * 72 + kk * 32 + g * 8];
        ao[h8] = mfma16x16(pf[kk], vf, ao[h8]);
      }

    if (nxt) {  // T14: commit prefetched tile after everyone is done reading
      __syncthreads();
#pragma unroll
      for (int p = 0; p < 4; ++p)
        *(u16x8*)&Kl[(p * 16 + krow) * 136 + kcol] = kreg[p];
#pragma unroll
      for (int p = 0; p < 4; ++p)
        *(u16x8*)&Vl[(p * 32 + vrow) * 72 + vcol] = vreg[p];
      __syncthreads();
    }
  }

  if (!split) {
    float inv[4];
#pragma unroll
    for (int r = 0; r < 4; ++r) inv[r] = 1.f / l_run[r];
    float* Og = out + (size_t)(b * T_DIM + rowq) * H_DIM;
#pragma unroll
    for (int h8 = 0; h8 < 8; ++h8)
#pragma unroll
      for (int r = 0; r < 4; ++r)
        Og[(size_t)(g * 4 + r) * H_DIM + h8 * 16 + lq] = ao[h8][r] * inv[r];
  } else {
    u16* Op = Opart + (size_t)pid * 8192 + (size_t)(wave * 16) * H_DIM;
#pragma unroll
    for (int h8 = 0; h8 < 8; ++h8)
#pragma unroll
      for (int r = 0; r < 4; ++r)
        Op[(g * 4 + r) * H_DIM + h8 * 16 + lq] = f2bf(ao[h8][r]);
    if (lq == 0) {
      float* mlp = ml + (size_t)pid * 128;
#pragma unroll
      for (int r = 0; r < 4; ++r) {
        mlp[wave * 16 + g * 4 + r] = m_run[r];
        mlp[64 + wave * 16 + g * 4 + r] = l_run[r];
      }
    }
  }
}

// --------------------------------------------------------------- combine ----
// grid (64, 4): merge the <=8 kv-split bf16 partials of one 64-row q-tile.
__global__ __launch_bounds__(256) void combine_kernel(
    const u16* __restrict__ Opart, const float* __restrict__ ml,
    float* __restrict__ out) {
  const int qt = blockIdx.x, b = blockIdx.y;
  const int t = threadIdx.x;
  const int row = t >> 2;
  const int colb = (t & 3) * 32;
  const int gg = qt >> 3;
  const int n = gg + 1;
  const int base_e = 4 * gg * (gg + 1) + (qt - 8 * gg) * n;
  const int pid0 = b * NPB + base_e;

  float mv[8];
#pragma unroll
  for (int i = 0; i < 8; ++i)
    mv[i] = (i < n) ? ml[(size_t)(pid0 + i) * 128 + row] : -INFINITY;
  float M = mv[0];
#pragma unroll
  for (int i = 1; i < 8; ++i) M = fmaxf(M, mv[i]);

  float L = 0.f;
  float o[32] = {};
#pragma unroll
  for (int i = 0; i < 8; ++i)
    if (i < n) {
      float sc = __expf(mv[i] - M);
      L += sc * ml[(size_t)(pid0 + i) * 128 + 64 + row];
      const u16* Op = Opart + (size_t)(pid0 + i) * 8192 + row * H_DIM + colb;
#pragma unroll
      for (int p = 0; p < 4; ++p) {
        u16x8 v = *(const u16x8*)&Op[p * 8];
#pragma unroll
        for (int e = 0; e < 8; ++e) o[p * 8 + e] += sc * bf2f(v[e]);
      }
    }
  float inv = 1.f / L;
  float* Og = out + ((size_t)b * T_DIM + qt * 64 + row) * H_DIM + colb;
#pragma unroll
  for (int p = 0; p < 8; ++p) {
    f32x4 v = {o[p * 4] * inv, o[p * 4 + 1] * inv, o[p * 4 + 2] * inv,
               o[p * 4 + 3] * inv};
    *(f32x4*)&Og[p * 4] = v;
  }
}

// ---------------------------------------------------------------- launch ----
extern "C" void kernel_launch(void* const* d_in, const int* in_sizes, int n_in,
                              void* d_out, int out_size, void* d_ws,
                              size_t ws_size, hipStream_t stream) {
  const float* x = (const float*)d_in[0];
  const float* wk = (const float*)d_in[1];
  const float* wq = (const float*)d_in[2];
  const float* wv = (const float*)d_in[3];
  float* out = (float*)d_out;
  char* ws = (char*)d_ws;

  u16* Wt = (u16*)ws;
  u16* Qb = (u16*)(ws + 786432);
  u16* Kb = (u16*)(ws + 786432 + 4194304);
  u16* Vt = (u16*)(ws + 786432 + 8388608);
  u16* Opart = (u16*)(ws + 13369344);
  float* ml = (float*)(ws + 32243712);

  const int split = (ws_size >= WS_SPLIT_NEED) ? 1 : 0;

  prep_w_kernel<<<dim3(16, 3), 256, 0, stream>>>(wk, wq, wv, Wt);
  proj_kernel<<<256, 256, 0, stream>>>(x, Wt, Qb, Kb, Vt);
  if (split) {
    attn_kernel<<<4 * NPB, 256, 0, stream>>>(Qb, Kb, Vt, out, Opart, ml, 1);
    combine_kernel<<<dim3(64, 4), 256, 0, stream>>>(Opart, ml, out);
  } else {
    attn_kernel<<<256, 256, 0, stream>>>(Qb, Kb, Vt, out, Opart, ml, 0);
  }
}